// Round 1
// baseline (4468.909 us; speedup 1.0000x reference)
//
#include <hip/hip_runtime.h>

typedef __attribute__((ext_vector_type(8))) short bf16x8;
typedef __attribute__((ext_vector_type(4))) float f32x4;
typedef unsigned short ushort_t;
typedef unsigned int uint32;

static constexpr int Bsz = 8;       // batch
static constexpr int T   = 8192;    // sequence length
static constexpr int Dd  = 128;     // head dim
static constexpr int NB  = 8;       // number of chunks (block_size)
static constexpr int N   = T / NB;  // 1024 tokens per chunk
static constexpr int Mt  = 64;      // query-tile rows per workgroup
static constexpr int Nk  = 64;      // key-tile columns

__device__ __forceinline__ float bf2f(ushort_t u){
  return __uint_as_float(((uint32)u) << 16);
}
__device__ __forceinline__ ushort_t f2bf(float f){
  uint32 u = __float_as_uint(f);
  u += 0x7FFFu + ((u >> 16) & 1u);   // RNE
  return (ushort_t)(u >> 16);
}

// ---------------------------------------------------------------------------
// QKV projection: out = bf16( (X @ W + bias) * scale ), X fp32 (nt x 128)
// grid.x = nt/64, 256 threads. MFMA 16x16x32 bf16.
// ---------------------------------------------------------------------------
__global__ __launch_bounds__(256)
void proj_kernel(const float* __restrict__ X,
                 const float* __restrict__ W,
                 const float* __restrict__ bias,
                 ushort_t* __restrict__ out,
                 float scale)
{
  __shared__ short Xt[Mt*Dd];    // [64][128] bf16, XOR-swizzled (16KB)
  __shared__ short Wt[Dd*Dd];    // Wt[col][k] bf16, XOR-swizzled (32KB)

  const int tid  = threadIdx.x;
  const int wave = tid >> 6;
  const int lane = tid & 63;
  const int lg   = lane >> 4;
  const int lr   = lane & 15;
  const int row0 = blockIdx.x * Mt;

  // stage W transposed: Wt[j][k] = W[k][j]
  for (int c = tid; c < Dd*32; c += 256){
    int k  = c >> 5;
    int j0 = (c & 31) * 4;
    const float4 w = *reinterpret_cast<const float4*>(W + (size_t)k*Dd + j0);
    const float* wf = reinterpret_cast<const float*>(&w);
    #pragma unroll
    for (int e = 0; e < 4; e++){
      int jj = j0 + e;
      int inner = (k & 7) | (((k >> 3) ^ (jj & 7)) << 3);
      Wt[jj*Dd + inner] = (short)f2bf(wf[e]);
    }
  }
  // stage X tile (row-major, swizzled 8-blocks along k)
  for (int c = tid; c < Mt*32; c += 256){
    int r  = c >> 5;
    int k0 = (c & 31) * 4;
    const float4 xv = *reinterpret_cast<const float4*>(X + (size_t)(row0 + r)*Dd + k0);
    const float* xf = reinterpret_cast<const float*>(&xv);
    int swz  = (k0 >> 3) ^ (r & 7);
    int base = r*Dd + swz*8 + (k0 & 7);
    #pragma unroll
    for (int e = 0; e < 4; e++) Xt[base + e] = (short)f2bf(xf[e]);
  }
  __syncthreads();

  f32x4 acc[8];
  #pragma unroll
  for (int nf = 0; nf < 8; nf++) acc[nf] = (f32x4){0.f,0.f,0.f,0.f};

  #pragma unroll
  for (int kk = 0; kk < 4; kk++){
    int arow = wave*16 + lr;
    int swz  = (lg + kk*4) ^ (lr & 7);
    bf16x8 a = *reinterpret_cast<const bf16x8*>(&Xt[arow*Dd + swz*8]);
    #pragma unroll
    for (int nf = 0; nf < 8; nf++){
      int col  = nf*16 + lr;
      bf16x8 b = *reinterpret_cast<const bf16x8*>(&Wt[col*Dd + swz*8]);
      acc[nf] = __builtin_amdgcn_mfma_f32_16x16x32_bf16(a, b, acc[nf], 0, 0, 0);
    }
  }

  #pragma unroll
  for (int nf = 0; nf < 8; nf++){
    int col = nf*16 + lr;
    float bia = bias[col];
    #pragma unroll
    for (int r = 0; r < 4; r++){
      int grow = row0 + wave*16 + lg*4 + r;
      float v = (acc[nf][r] + bia) * scale;
      out[(size_t)grow*Dd + col] = f2bf(v);
    }
  }
}

// ---------------------------------------------------------------------------
// Unified flash kernel.
// MODE 0 (Phase B / _init_state for block iblk):
//   queries = Qb[block iblk]; keys = Kb[blocks 0..iblk];
//   values  = VcF (fp32, split hi/lo) for j<iblk, Vb for j==iblk.
//   writes m,d,VcF for block iblk rows.
// MODE 1 (Phase A / _update_state, one old block j per wg group):
//   queries = Kb[block j]; keys = Qb[block iblk]; values = Vb[block iblk];
//   merges with old (m,d), updates VcF rows in place (faithful ratio form).
// ---------------------------------------------------------------------------
template<int MODE>
__global__ __launch_bounds__(256)
void attn_phase(const ushort_t* __restrict__ Qb,
                const ushort_t* __restrict__ Kb,
                const ushort_t* __restrict__ Vb,
                float* __restrict__ VcF,
                float* __restrict__ m_st,
                float* __restrict__ d_st,
                int iblk)
{
  __shared__ short Kt [Mt*Dd];   // key tile  [64][128], swizzled (16KB)
  __shared__ short Vt0[Dd*Nk];   // V^T hi    [128][64], swizzled (16KB)
  __shared__ short Vt1[Dd*Nk];   // V^T lo    [128][64], swizzled (16KB)
  __shared__ short Pt [Mt*Nk];   // P tile    [64][64],  swizzled (8KB)

  const int tid  = threadIdx.x;
  const int wave = tid >> 6;
  const int lane = tid & 63;
  const int lg   = lane >> 4;
  const int lr   = lane & 15;

  int b, qrow0, nkt;
  if (MODE == 0){
    int bi = blockIdx.x; b = bi >> 4; int qt = bi & 15;
    qrow0 = b*T + iblk*N + qt*Mt;
    nkt   = (iblk + 1) * (N / Nk);
  } else {
    int per = iblk * (N / Nk);
    int bi = blockIdx.x; b = bi / per; int rem = bi - b*per;
    int j = rem >> 4, ot = rem & 15;
    qrow0 = b*T + j*N + ot*Mt;
    nkt   = N / Nk;
  }

  const ushort_t* qsrc = (MODE == 0) ? Qb : Kb;
  const ushort_t* ksrc = (MODE == 0) ? Kb : Qb;

  // load Q A-fragments (A: row = lane&15, k = 8*(lane>>4)+e, contiguous)
  bf16x8 aq[4];
  {
    const ushort_t* qp = qsrc + (size_t)(qrow0 + wave*16 + lr)*Dd + lg*8;
    #pragma unroll
    for (int kk = 0; kk < 4; kk++)
      aq[kk] = *reinterpret_cast<const bf16x8*>(qp + kk*32);
  }

  f32x4 acc[8];
  #pragma unroll
  for (int cf = 0; cf < 8; cf++) acc[cf] = (f32x4){0.f,0.f,0.f,0.f};
  float m_run[4] = {-INFINITY, -INFINITY, -INFINITY, -INFINITY};
  float d_run[4] = {0.f, 0.f, 0.f, 0.f};

  for (int t = 0; t < nkt; ++t){
    int j  = (MODE == 0) ? (t >> 4) : iblk;
    int kt = (MODE == 0) ? (t & 15) : t;
    int krow0 = b*T + j*N + kt*Nk;
    const bool haslo = (MODE == 0) && (j < iblk);

    __syncthreads();   // previous tile fully consumed

    // stage key tile (bf16 rows, swizzled 8-blocks along k)
    for (int c = tid; c < Mt*16; c += 256){
      int r = c >> 4, kb = c & 15;
      bf16x8 v = *reinterpret_cast<const bf16x8*>(ksrc + (size_t)(krow0 + r)*Dd + kb*8);
      int swz = kb ^ (r & 7);
      *reinterpret_cast<bf16x8*>(&Kt[r*Dd + swz*8]) = v;
    }
    // stage value tile, transposed into Vt[d][r]
    if (haslo){
      // fp32 Vc -> hi/lo bf16 split
      for (int c = tid; c < Nk*32; c += 256){
        int r = c >> 5, d0 = (c & 31) * 4;
        const float4 v = *reinterpret_cast<const float4*>(VcF + (size_t)(krow0 + r)*Dd + d0);
        const float* vf = reinterpret_cast<const float*>(&v);
        #pragma unroll
        for (int e = 0; e < 4; e++){
          int d = d0 + e;
          float f = vf[e];
          ushort_t hi = f2bf(f);
          ushort_t lo = f2bf(f - bf2f(hi));
          int inner = (r & 7) | (((r >> 3) ^ (d & 7)) << 3);
          Vt0[d*Nk + inner] = (short)hi;
          Vt1[d*Nk + inner] = (short)lo;
        }
      }
    } else {
      for (int c = tid; c < Nk*16; c += 256){
        int r = c >> 4, db = c & 15; int d0 = db*8;
        bf16x8 v = *reinterpret_cast<const bf16x8*>(Vb + (size_t)(krow0 + r)*Dd + d0);
        #pragma unroll
        for (int e = 0; e < 8; e++){
          int d = d0 + e;
          int inner = (r & 7) | (((r >> 3) ^ (d & 7)) << 3);
          Vt0[d*Nk + inner] = v[e];
        }
      }
    }
    __syncthreads();

    // S = Q · K^T (scale pre-folded into Q)
    f32x4 s[4];
    #pragma unroll
    for (int nf = 0; nf < 4; nf++) s[nf] = (f32x4){0.f,0.f,0.f,0.f};
    #pragma unroll
    for (int kk = 0; kk < 4; kk++){
      #pragma unroll
      for (int nf = 0; nf < 4; nf++){
        int row = nf*16 + lr;
        int swz = (lg + kk*4) ^ (lr & 7);
        bf16x8 bk = *reinterpret_cast<const bf16x8*>(&Kt[row*Dd + swz*8]);
        s[nf] = __builtin_amdgcn_mfma_f32_16x16x32_bf16(aq[kk], bk, s[nf], 0, 0, 0);
      }
    }

    // online softmax (rows live on the 16 lanes sharing lg; reduce over lr)
    float ps[4];
    #pragma unroll
    for (int r = 0; r < 4; r++){
      float v = fmaxf(fmaxf(s[0][r], s[1][r]), fmaxf(s[2][r], s[3][r]));
      #pragma unroll
      for (int off = 1; off < 16; off <<= 1) v = fmaxf(v, __shfl_xor(v, off));
      float mn = fmaxf(m_run[r], v);
      float sc = __expf(m_run[r] - mn);
      d_run[r] *= sc;
      m_run[r] = mn;
      #pragma unroll
      for (int cf = 0; cf < 8; cf++) acc[cf][r] *= sc;
      ps[r] = 0.f;
    }
    #pragma unroll
    for (int nf = 0; nf < 4; nf++){
      #pragma unroll
      for (int r = 0; r < 4; r++){
        float p = __expf(s[nf][r] - m_run[r]);
        ps[r] += p;
        int prow = wave*16 + lg*4 + r;     // D-layout row
        int pcol = nf*16 + lr;             // D-layout col
        int inner = (pcol & 7) | (((pcol >> 3) ^ (prow & 7)) << 3);
        Pt[prow*Nk + inner] = (short)f2bf(p);
      }
    }
    #pragma unroll
    for (int r = 0; r < 4; r++){
      float v = ps[r];
      #pragma unroll
      for (int off = 1; off < 16; off <<= 1) v += __shfl_xor(v, off);
      d_run[r] += v;
    }
    __syncthreads();

    // acc += P @ V  (A-frags of P from LDS; B-frags from transposed V)
    bf16x8 ap[2];
    #pragma unroll
    for (int kk = 0; kk < 2; kk++){
      int row = wave*16 + lr;
      int swz = (lg + kk*4) ^ (lr & 7);
      ap[kk] = *reinterpret_cast<const bf16x8*>(&Pt[row*Nk + swz*8]);
    }
    #pragma unroll
    for (int cf = 0; cf < 8; cf++){
      #pragma unroll
      for (int kk = 0; kk < 2; kk++){
        int dcol = cf*16 + lr;
        int swz  = (lg + kk*4) ^ (lr & 7);
        bf16x8 bv = *reinterpret_cast<const bf16x8*>(&Vt0[dcol*Nk + swz*8]);
        acc[cf] = __builtin_amdgcn_mfma_f32_16x16x32_bf16(ap[kk], bv, acc[cf], 0, 0, 0);
      }
    }
    if (haslo){
      #pragma unroll
      for (int cf = 0; cf < 8; cf++){
        #pragma unroll
        for (int kk = 0; kk < 2; kk++){
          int dcol = cf*16 + lr;
          int swz  = (lg + kk*4) ^ (lr & 7);
          bf16x8 bv = *reinterpret_cast<const bf16x8*>(&Vt1[dcol*Nk + swz*8]);
          acc[cf] = __builtin_amdgcn_mfma_f32_16x16x32_bf16(ap[kk], bv, acc[cf], 0, 0, 0);
        }
      }
    }
  }

  // epilogue
  if (MODE == 0){
    #pragma unroll
    for (int r = 0; r < 4; r++){
      int grow = qrow0 + wave*16 + lg*4 + r;
      float dinv = 1.f / d_run[r];
      #pragma unroll
      for (int cf = 0; cf < 8; cf++){
        int col = cf*16 + lr;
        VcF[(size_t)grow*Dd + col] = acc[cf][r] * dinv;
      }
      if (lr == 0){ m_st[grow] = m_run[r]; d_st[grow] = d_run[r]; }
    }
  } else {
    #pragma unroll
    for (int r = 0; r < 4; r++){
      int grow = qrow0 + wave*16 + lg*4 + r;
      float mo   = m_st[grow];
      float dold = d_st[grow];
      float mn   = fmaxf(mo, m_run[r]);
      float se   = __expf(m_run[r] - mn);      // rescale running acc/d to mn
      float nd   = dold * __expf(mo - mn) + d_run[r] * se;
      float ratio = nd / dold;                  // faithful to reference
      float accm  = se / nd;
      #pragma unroll
      for (int cf = 0; cf < 8; cf++){
        int col = cf*16 + lr;
        size_t idx = (size_t)grow*Dd + col;
        float oldv = VcF[idx];
        VcF[idx] = ratio * oldv + acc[cf][r] * accm;
      }
      if (lr == 0){ m_st[grow] = mn; d_st[grow] = nd; }
    }
  }
}

// ---------------------------------------------------------------------------
extern "C" void kernel_launch(void* const* d_in, const int* in_sizes, int n_in,
                              void* d_out, int out_size, void* d_ws, size_t ws_size,
                              hipStream_t stream)
{
  (void)in_sizes; (void)n_in; (void)out_size; (void)ws_size;

  const float* x  = (const float*)d_in[0];
  const float* Wq = (const float*)d_in[1];
  const float* bq = (const float*)d_in[2];
  const float* Wk = (const float*)d_in[3];
  const float* bk = (const float*)d_in[4];
  const float* Wv = (const float*)d_in[5];
  const float* bv = (const float*)d_in[6];
  // d_in[7] = block_size (8) -- hard-coded via NB.

  float* VcF = (float*)d_out;    // fp32 v_cache state lives directly in d_out

  char* ws = (char*)d_ws;
  const size_t nt = (size_t)Bsz * T;   // 65536 rows
  ushort_t* Qb = (ushort_t*)ws;  ws += nt * Dd * sizeof(ushort_t);
  ushort_t* Kb = (ushort_t*)ws;  ws += nt * Dd * sizeof(ushort_t);
  ushort_t* Vb = (ushort_t*)ws;  ws += nt * Dd * sizeof(ushort_t);
  float* m_st  = (float*)ws;     ws += nt * sizeof(float);
  float* d_st  = (float*)ws;     ws += nt * sizeof(float);

  const float scale = 0.08838834764831845f;   // 1/sqrt(128), folded into Q
  dim3 blk(256);
  const int ngrid = (int)(nt / Mt);           // 1024

  proj_kernel<<<ngrid, blk, 0, stream>>>(x, Wq, bq, Qb, scale);
  proj_kernel<<<ngrid, blk, 0, stream>>>(x, Wk, bk, Kb, 1.0f);
  proj_kernel<<<ngrid, blk, 0, stream>>>(x, Wv, bv, Vb, 1.0f);

  for (int i = 0; i < NB; i++){
    // Phase B first (reads old Vc rows), then Phase A (updates them in place).
    attn_phase<0><<<Bsz * (N / Mt), blk, 0, stream>>>(Qb, Kb, Vb, VcF, m_st, d_st, i);
    if (i > 0)
      attn_phase<1><<<Bsz * i * (N / Mt), blk, 0, stream>>>(Qb, Kb, Vb, VcF, m_st, d_st, i);
  }
}

// Round 2
// 1128.317 us; speedup vs baseline: 3.9607x; 3.9607x over previous
//
#include <hip/hip_runtime.h>

typedef __attribute__((ext_vector_type(8))) short bf16x8;
typedef __attribute__((ext_vector_type(4))) float f32x4;
typedef unsigned short ushort_t;
typedef unsigned int uint32;

static constexpr int Bsz = 8;       // batch
static constexpr int T   = 8192;    // sequence length
static constexpr int Dd  = 128;     // head dim
static constexpr int NB  = 8;       // chunks
static constexpr int N   = T / NB;  // 1024 tokens per chunk
static constexpr int Mt  = 64;      // rows per workgroup tile
static constexpr int Nk  = 64;      // keys per tile
static constexpr int TPC = N / Nk;  // 16 tiles per chunk

__device__ __forceinline__ float bf2f(ushort_t u){
  return __uint_as_float(((uint32)u) << 16);
}
__device__ __forceinline__ ushort_t f2bf(float f){
  uint32 u = __float_as_uint(f);
  u += 0x7FFFu + ((u >> 16) & 1u);   // RNE
  return (ushort_t)(u >> 16);
}

// ---------------------------------------------------------------------------
// Projection: grid (nt/64, 3).  y=0: Qb=(XWq+bq)*scale row-major bf16
//                               y=1: Kb=(XWk+bk) row-major bf16
//                               y=2: VbT=(XWv+bv) TRANSPOSED [b][d][t] bf16
// ---------------------------------------------------------------------------
__global__ __launch_bounds__(256)
void proj_kernel(const float* __restrict__ X,
                 const float* __restrict__ Wq, const float* __restrict__ bq,
                 const float* __restrict__ Wk, const float* __restrict__ bk,
                 const float* __restrict__ Wv, const float* __restrict__ bv,
                 ushort_t* __restrict__ Qb, ushort_t* __restrict__ Kb,
                 ushort_t* __restrict__ VbT, float scale)
{
  __shared__ __align__(16) char smem[49152];
  short* Xt = (short*)smem;             // 16KB [64][128] swz
  short* Wt = (short*)(smem + 16384);   // 32KB [col][k] swz
  float* Brot = (float*)smem;           // 32KB overlay (V bounce)

  const int which = blockIdx.y;
  const float* W   = (which == 0) ? Wq : (which == 1) ? Wk : Wv;
  const float* bia = (which == 0) ? bq : (which == 1) ? bk : bv;
  const float sc   = (which == 0) ? scale : 1.0f;

  const int tid  = threadIdx.x;
  const int wave = tid >> 6;
  const int lane = tid & 63;
  const int lg   = lane >> 4;
  const int lr   = lane & 15;
  const int row0 = blockIdx.x * Mt;

  // stage W transposed: Wt[j][k] = W[k][j]
  for (int c = tid; c < Dd*32; c += 256){
    int k  = c >> 5;
    int j0 = (c & 31) * 4;
    const float4 w = *reinterpret_cast<const float4*>(W + (size_t)k*Dd + j0);
    const float* wf = reinterpret_cast<const float*>(&w);
    #pragma unroll
    for (int e = 0; e < 4; e++){
      int jj = j0 + e;
      int inner = (k & 7) | (((k >> 3) ^ (jj & 7)) << 3);
      Wt[jj*Dd + inner] = (short)f2bf(wf[e]);
    }
  }
  for (int c = tid; c < Mt*32; c += 256){
    int r  = c >> 5;
    int k0 = (c & 31) * 4;
    const float4 xv = *reinterpret_cast<const float4*>(X + (size_t)(row0 + r)*Dd + k0);
    const float* xf = reinterpret_cast<const float*>(&xv);
    int swz  = (k0 >> 3) ^ (r & 7);
    int base = r*Dd + swz*8 + (k0 & 7);
    #pragma unroll
    for (int e = 0; e < 4; e++) Xt[base + e] = (short)f2bf(xf[e]);
  }
  __syncthreads();

  f32x4 acc[8];
  #pragma unroll
  for (int nf = 0; nf < 8; nf++) acc[nf] = (f32x4){0.f,0.f,0.f,0.f};

  #pragma unroll
  for (int kk = 0; kk < 4; kk++){
    int arow = wave*16 + lr;
    int swz  = (lg + kk*4) ^ (lr & 7);
    bf16x8 a = *reinterpret_cast<const bf16x8*>(&Xt[arow*Dd + swz*8]);
    #pragma unroll
    for (int nf = 0; nf < 8; nf++){
      int col  = nf*16 + lr;
      bf16x8 b = *reinterpret_cast<const bf16x8*>(&Wt[col*Dd + swz*8]);
      acc[nf] = __builtin_amdgcn_mfma_f32_16x16x32_bf16(a, b, acc[nf], 0, 0, 0);
    }
  }

  if (which < 2){
    ushort_t* out = (which == 0) ? Qb : Kb;
    #pragma unroll
    for (int nf = 0; nf < 8; nf++){
      int col = nf*16 + lr;
      float bv_ = bia[col];
      #pragma unroll
      for (int r = 0; r < 4; r++){
        int grow = row0 + wave*16 + lg*4 + r;
        out[(size_t)grow*Dd + col] = f2bf((acc[nf][r] + bv_) * sc);
      }
    }
  } else {
    // bounce to transposed layout
    __syncthreads();
    #pragma unroll
    for (int nf = 0; nf < 8; nf++){
      int col = nf*16 + lr;
      float bv_ = bia[col];
      #pragma unroll
      for (int r = 0; r < 4; r++){
        int row_l = wave*16 + lg*4 + r;
        Brot[row_l*Dd + ((col + row_l) & 127)] = acc[nf][r] + bv_;
      }
    }
    __syncthreads();
    const int bb  = row0 >> 13;          // /T
    const int tq0 = row0 & (T - 1);
    const size_t vb = (size_t)bb * Dd * T;
    #pragma unroll 4
    for (int dd = 0; dd < 32; ++dd){
      int d = wave*32 + dd;
      float v = Brot[lane*Dd + ((d + lane) & 127)];
      VbT[vb + (size_t)d*T + tq0 + lane] = f2bf(v);
    }
  }
}

// ---------------------------------------------------------------------------
// Unified per-iteration attention step.
// First 128*(iblk+1) wgs: _init_state split-KV partials for block iblk:
//   (b, qt, j): queries=Q[iblk], keys=K[j], values = j<iblk ? VcT(read) : VbT.
//   -> Pacc/Pm/Pd[j].
// Next 128*iblk wgs: _update_state for old block jold vs new block iblk:
//   queries=K[jold], keys=Q[iblk], values=VbT[iblk]; faithful ratio update of
//   VcF rows in place + writes hi/lo transposed copy into VcT(write).
// ---------------------------------------------------------------------------
__global__ __launch_bounds__(256)
void attn_step(const ushort_t* __restrict__ Qb, const ushort_t* __restrict__ Kb,
               const ushort_t* __restrict__ VbT,
               const ushort_t* __restrict__ VcTr_hi, const ushort_t* __restrict__ VcTr_lo,
               ushort_t* __restrict__ VcTw_hi, ushort_t* __restrict__ VcTw_lo,
               float* __restrict__ VcF, float* __restrict__ m_st, float* __restrict__ d_st,
               float* __restrict__ Pacc, float* __restrict__ Pm, float* __restrict__ Pd,
               int iblk)
{
  __shared__ __align__(16) char smem[40960];
  short* Kt = (short*)smem;             // 16KB [64][128] swz
  short* Vt = (short*)(smem + 16384);   // 16KB [128][64] swz (hi, then lo)
  short* Pt = (short*)(smem + 32768);   // 8KB  [64][64]  swz
  float* Brot = (float*)smem;           // 32KB overlay (update bounce)

  const int tid  = threadIdx.x;
  const int wave = tid >> 6;
  const int lane = tid & 63;
  const int lg   = lane >> 4;
  const int lr   = lane & 15;

  const int g0 = Bsz * 16 * (iblk + 1);
  const int bi = blockIdx.x;
  const bool is0 = (bi < g0);

  int b, qrow0, t0, j, prow0;
  bool haslo;
  const ushort_t *qsrc, *ksrc, *vhi;

  if (is0){
    j = bi >> 7;
    int rem = bi & 127;
    b = rem >> 4;
    int qt = rem & 15;
    qrow0 = b*T + iblk*N + qt*Mt;
    prow0 = (b*16 + qt)*Mt;
    t0 = j*N;
    haslo = (j < iblk);
    qsrc = Qb; ksrc = Kb;
    vhi = haslo ? VcTr_hi : VbT;
  } else {
    int bi2 = bi - g0;
    int per = 16 * iblk;
    b = bi2 / per;
    int rem = bi2 - b*per;
    int jold = rem >> 4;
    int ot = rem & 15;
    qrow0 = b*T + jold*N + ot*Mt;
    prow0 = 0;
    t0 = iblk*N;
    haslo = false;
    qsrc = Kb; ksrc = Qb;
    vhi = VbT;
    j = jold;
  }
  const int krow0base = b*T + t0;
  const size_t vbase = (size_t)b * Dd * T;
  const ushort_t* vhiB = vhi + vbase;
  const ushort_t* vloB = VcTr_lo + vbase;   // only read when haslo

  // query A-fragments (row = lane&15, k = kk*32 + lg*8 + e)
  bf16x8 aq[4];
  {
    const ushort_t* qp = qsrc + (size_t)(qrow0 + wave*16 + lr)*Dd + lg*8;
    #pragma unroll
    for (int kk = 0; kk < 4; ++kk) aq[kk] = *reinterpret_cast<const bf16x8*>(qp + kk*32);
  }

  f32x4 acc[8];
  #pragma unroll
  for (int cf = 0; cf < 8; ++cf) acc[cf] = (f32x4){0.f,0.f,0.f,0.f};
  float m_run[4] = {-INFINITY,-INFINITY,-INFINITY,-INFINITY};
  float d_run[4] = {0.f,0.f,0.f,0.f};

  for (int kt = 0; kt < TPC; ++kt){
    const int krow0 = krow0base + kt*Nk;
    const int tt0   = t0 + kt*Nk;

    __syncthreads();
    // stage key tile rows (bf16, swizzled)
    #pragma unroll
    for (int it = 0; it < 4; ++it){
      int c = tid + it*256;
      int r = c >> 4, kb = c & 15;
      bf16x8 v = *reinterpret_cast<const bf16x8*>(ksrc + (size_t)(krow0 + r)*Dd + kb*8);
      *reinterpret_cast<bf16x8*>(&Kt[r*Dd + ((kb ^ (r & 7)))*8]) = v;
    }
    // stage value tile from pre-transposed source (straight copy, swizzled)
    #pragma unroll
    for (int it = 0; it < 4; ++it){
      int c = tid + it*256;
      int d = c >> 3, sg = c & 7;
      bf16x8 v = *reinterpret_cast<const bf16x8*>(vhiB + (size_t)d*T + tt0 + sg*8);
      *reinterpret_cast<bf16x8*>(&Vt[d*Nk + ((sg ^ (d & 7)))*8]) = v;
    }
    __syncthreads();

    // S = Q · K^T
    f32x4 s[4];
    #pragma unroll
    for (int nf = 0; nf < 4; ++nf) s[nf] = (f32x4){0.f,0.f,0.f,0.f};
    #pragma unroll
    for (int kk = 0; kk < 4; ++kk){
      int sg = kk*4 + lg;
      #pragma unroll
      for (int nf = 0; nf < 4; ++nf){
        int row = nf*16 + lr;
        bf16x8 bk = *reinterpret_cast<const bf16x8*>(&Kt[row*Dd + ((sg ^ (lr & 7)))*8]);
        s[nf] = __builtin_amdgcn_mfma_f32_16x16x32_bf16(aq[kk], bk, s[nf], 0, 0, 0);
      }
    }

    // online softmax
    float ps[4];
    #pragma unroll
    for (int r = 0; r < 4; ++r){
      float v = fmaxf(fmaxf(s[0][r], s[1][r]), fmaxf(s[2][r], s[3][r]));
      #pragma unroll
      for (int off = 1; off < 16; off <<= 1) v = fmaxf(v, __shfl_xor(v, off));
      float mn = fmaxf(m_run[r], v);
      float scl = __expf(m_run[r] - mn);
      d_run[r] *= scl;
      m_run[r] = mn;
      #pragma unroll
      for (int cf = 0; cf < 8; ++cf) acc[cf][r] *= scl;
      ps[r] = 0.f;
    }
    #pragma unroll
    for (int nf = 0; nf < 4; ++nf){
      #pragma unroll
      for (int r = 0; r < 4; ++r){
        float p = __expf(s[nf][r] - m_run[r]);
        ps[r] += p;
        int prow = wave*16 + lg*4 + r;
        int pcol = nf*16 + lr;
        Pt[prow*Nk + (pcol & 7) + (((pcol >> 3) ^ (prow & 7)) << 3)] = (short)f2bf(p);
      }
    }
    #pragma unroll
    for (int r = 0; r < 4; ++r){
      float v = ps[r];
      #pragma unroll
      for (int off = 1; off < 16; off <<= 1) v += __shfl_xor(v, off);
      d_run[r] += v;
    }
    __syncthreads();

    // acc += P @ V(hi)
    bf16x8 ap[2];
    #pragma unroll
    for (int kk = 0; kk < 2; ++kk){
      int row = wave*16 + lr;
      ap[kk] = *reinterpret_cast<const bf16x8*>(&Pt[row*Nk + (((kk*4 + lg) ^ (lr & 7)))*8]);
    }
    #pragma unroll
    for (int cf = 0; cf < 8; ++cf){
      #pragma unroll
      for (int kk = 0; kk < 2; ++kk){
        int dcol = cf*16 + lr;
        bf16x8 bv = *reinterpret_cast<const bf16x8*>(&Vt[dcol*Nk + (((kk*4 + lg) ^ (lr & 7)))*8]);
        acc[cf] = __builtin_amdgcn_mfma_f32_16x16x32_bf16(ap[kk], bv, acc[cf], 0, 0, 0);
      }
    }
    if (haslo){
      // low half of fp32 value cache, staged into the same buffer
      __syncthreads();
      #pragma unroll
      for (int it = 0; it < 4; ++it){
        int c = tid + it*256;
        int d = c >> 3, sg = c & 7;
        bf16x8 v = *reinterpret_cast<const bf16x8*>(vloB + (size_t)d*T + tt0 + sg*8);
        *reinterpret_cast<bf16x8*>(&Vt[d*Nk + ((sg ^ (d & 7)))*8]) = v;
      }
      __syncthreads();
      #pragma unroll
      for (int cf = 0; cf < 8; ++cf){
        #pragma unroll
        for (int kk = 0; kk < 2; ++kk){
          int dcol = cf*16 + lr;
          bf16x8 bv = *reinterpret_cast<const bf16x8*>(&Vt[dcol*Nk + (((kk*4 + lg) ^ (lr & 7)))*8]);
          acc[cf] = __builtin_amdgcn_mfma_f32_16x16x32_bf16(ap[kk], bv, acc[cf], 0, 0, 0);
        }
      }
    }
  }

  if (is0){
    // split-KV partial write
    #pragma unroll
    for (int r = 0; r < 4; ++r){
      int pr = prow0 + wave*16 + lg*4 + r;
      float* pa = Pacc + ((size_t)j*8192 + pr)*Dd;
      #pragma unroll
      for (int cf = 0; cf < 8; ++cf) pa[cf*16 + lr] = acc[cf][r];
      if (lr == 0){ Pm[j*8192 + pr] = m_run[r]; Pd[j*8192 + pr] = d_run[r]; }
    }
  } else {
    // faithful _update_state merge, in place on VcF
    #pragma unroll
    for (int r = 0; r < 4; ++r){
      int grow = qrow0 + wave*16 + lg*4 + r;
      float mo = m_st[grow], dold = d_st[grow];
      float mn = fmaxf(mo, m_run[r]);
      float se = __expf(m_run[r] - mn);
      float nd = dold * __expf(mo - mn) + d_run[r] * se;
      float ratio = nd / dold;
      float accm  = se / nd;
      #pragma unroll
      for (int cf = 0; cf < 8; ++cf){
        size_t idx = (size_t)grow*Dd + cf*16 + lr;
        float v = ratio * VcF[idx] + acc[cf][r] * accm;
        VcF[idx] = v;
        acc[cf][r] = v;
      }
      if (lr == 0){ m_st[grow] = mn; d_st[grow] = nd; }
    }
    // bounce-transpose new Vc rows into VcT(write) hi/lo
    __syncthreads();
    #pragma unroll
    for (int cf = 0; cf < 8; ++cf){
      int col = cf*16 + lr;
      #pragma unroll
      for (int r = 0; r < 4; ++r){
        int row_l = wave*16 + lg*4 + r;
        Brot[row_l*Dd + ((col + row_l) & 127)] = acc[cf][r];
      }
    }
    __syncthreads();
    const int tq0 = qrow0 & (T - 1);
    #pragma unroll 4
    for (int dd = 0; dd < 32; ++dd){
      int d = wave*32 + dd;
      float v = Brot[lane*Dd + ((d + lane) & 127)];
      ushort_t hi = f2bf(v);
      VcTw_hi[vbase + (size_t)d*T + tq0 + lane] = hi;
      VcTw_lo[vbase + (size_t)d*T + tq0 + lane] = f2bf(v - bf2f(hi));
    }
  }
}

// ---------------------------------------------------------------------------
// Merge split-KV partials -> block iblk rows of VcF, m_st, d_st, VcT(write).
// grid = 128 (b, qt), 256 threads.
// ---------------------------------------------------------------------------
__global__ __launch_bounds__(256)
void merge_kernel(const float* __restrict__ Pacc, const float* __restrict__ Pm,
                  const float* __restrict__ Pd,
                  float* __restrict__ VcF, float* __restrict__ m_st, float* __restrict__ d_st,
                  ushort_t* __restrict__ VcTw_hi, ushort_t* __restrict__ VcTw_lo,
                  int iblk)
{
  __shared__ float Brot[Mt*Dd];   // 32KB rotation layout
  const int bi = blockIdx.x;
  const int b = bi >> 4, qt = bi & 15;
  const int tid = threadIdx.x;
  const int lrow = tid >> 2, dq = tid & 3;
  const int prow = (b*16 + qt)*Mt + lrow;
  const int grow = b*T + iblk*N + qt*Mt + lrow;

  float M = -INFINITY;
  for (int jj = 0; jj <= iblk; ++jj) M = fmaxf(M, Pm[jj*8192 + prow]);

  float out[32];
  #pragma unroll
  for (int e = 0; e < 32; ++e) out[e] = 0.f;
  float D = 0.f;
  for (int jj = 0; jj <= iblk; ++jj){
    float wj = __expf(Pm[jj*8192 + prow] - M);
    D += Pd[jj*8192 + prow] * wj;
    const float* pa = Pacc + ((size_t)jj*8192 + prow)*Dd + dq*32;
    #pragma unroll
    for (int e8 = 0; e8 < 8; ++e8){
      float4 v = *reinterpret_cast<const float4*>(pa + e8*4);
      out[e8*4+0] += v.x * wj;
      out[e8*4+1] += v.y * wj;
      out[e8*4+2] += v.z * wj;
      out[e8*4+3] += v.w * wj;
    }
  }
  float dinv = 1.f / D;
  #pragma unroll
  for (int e = 0; e < 32; ++e){
    int d = dq*32 + e;
    float v = out[e] * dinv;
    VcF[(size_t)grow*Dd + d] = v;
    Brot[lrow*Dd + ((d + lrow) & 127)] = v;
  }
  if (dq == 0){ m_st[grow] = M; d_st[grow] = D; }
  __syncthreads();

  const int wave = tid >> 6, lane = tid & 63;
  const int tq0 = iblk*N + qt*Mt;
  const size_t vb = (size_t)b * Dd * T;
  #pragma unroll 4
  for (int dd = 0; dd < 32; ++dd){
    int d = wave*32 + dd;
    float v = Brot[lane*Dd + ((d + lane) & 127)];
    ushort_t hi = f2bf(v);
    VcTw_hi[vb + (size_t)d*T + tq0 + lane] = hi;
    VcTw_lo[vb + (size_t)d*T + tq0 + lane] = f2bf(v - bf2f(hi));
  }
}

// ---------------------------------------------------------------------------
extern "C" void kernel_launch(void* const* d_in, const int* in_sizes, int n_in,
                              void* d_out, int out_size, void* d_ws, size_t ws_size,
                              hipStream_t stream)
{
  (void)in_sizes; (void)n_in; (void)out_size; (void)ws_size;

  const float* x  = (const float*)d_in[0];
  const float* Wq = (const float*)d_in[1];
  const float* bq = (const float*)d_in[2];
  const float* Wk = (const float*)d_in[3];
  const float* bk = (const float*)d_in[4];
  const float* Wv = (const float*)d_in[5];
  const float* bv = (const float*)d_in[6];

  float* VcF = (float*)d_out;          // fp32 master v_cache == output

  const size_t nt = (size_t)Bsz * T;   // 65536 rows
  char* p = (char*)d_ws;
  auto alloc = [&](size_t bytes) -> void* {
    void* r = (void*)p;
    p += (bytes + 255) & ~(size_t)255;
    return r;
  };
  ushort_t* Qb   = (ushort_t*)alloc(nt * Dd * 2);          // 16MB
  ushort_t* Kb   = (ushort_t*)alloc(nt * Dd * 2);          // 16MB
  ushort_t* VbT  = (ushort_t*)alloc(nt * Dd * 2);          // 16MB transposed raw V
  ushort_t* VcT[2][2];
  for (int c = 0; c < 2; ++c)
    for (int h = 0; h < 2; ++h)
      VcT[c][h] = (ushort_t*)alloc(nt * Dd * 2);           // 4 x 16MB
  float* m_st = (float*)alloc(nt * 4);
  float* d_st = (float*)alloc(nt * 4);
  float* Pacc = (float*)alloc((size_t)NB * 8192 * Dd * 4); // 33.5MB
  float* Pm   = (float*)alloc((size_t)NB * 8192 * 4);
  float* Pd   = (float*)alloc((size_t)NB * 8192 * 4);

  const float scale = 0.08838834764831845f;   // 1/sqrt(128), folded into Q
  dim3 blk(256);

  proj_kernel<<<dim3((unsigned)(nt / Mt), 3), blk, 0, stream>>>(
      x, Wq, bq, Wk, bk, Wv, bv, Qb, Kb, VbT, scale);

  for (int i = 0; i < NB; ++i){
    const int wb = i & 1, rb = wb ^ 1;
    const int grid = 128 * (2*i + 1);
    attn_step<<<grid, blk, 0, stream>>>(
        Qb, Kb, VbT,
        VcT[rb][0], VcT[rb][1], VcT[wb][0], VcT[wb][1],
        VcF, m_st, d_st, Pacc, Pm, Pd, i);
    merge_kernel<<<128, blk, 0, stream>>>(
        Pacc, Pm, Pd, VcF, m_st, d_st, VcT[wb][0], VcT[wb][1], i);
  }
}